// Round 14
// baseline (1797.338 us; speedup 1.0000x reference)
//
#include <hip/hip_runtime.h>
#include <math.h>

namespace {

constexpr int T_STEPS = 512;

typedef _Float16 h8v __attribute__((ext_vector_type(8)));
typedef _Float16 h2v __attribute__((ext_vector_type(2)));
typedef float    f4v __attribute__((ext_vector_type(4)));

// rcp-based activations (R13-proven: IEEE div was ~half the VALU issue).
__device__ __forceinline__ float sigf(float v) {
  return __builtin_amdgcn_rcpf(1.0f + __builtin_amdgcn_exp2f(-1.442695041f * v));
}
__device__ __forceinline__ float tanh_(float v) {
  return 2.0f * __builtin_amdgcn_rcpf(1.0f + __builtin_amdgcn_exp2f(-2.885390082f * v)) - 1.0f;
}

// Pack weights into MFMA B-fragment load order, fp16 (verified on HW R3-R13).
// PA (layer0): frag f = (w*4+q)*6 + ks: gate = 16*(8q+w)+(l&15),
//   k = 32*ks + 8*(l>>4) + j ; ks 0-1 Wih0, ks 2-5 Whh0.
// PB (layer1): 8 ks: 0-3 Wih1, 4-7 Whh1.
__global__ void pack_w(const float* __restrict__ Wih0, const float* __restrict__ Whh0,
                       const float* __restrict__ Wih1, const float* __restrict__ Whh1,
                       _Float16* __restrict__ PA, _Float16* __restrict__ PB) {
  int idx = blockIdx.x * 256 + threadIdx.x;
  if (idx < 98304) {
    int j = idx & 7, l = (idx >> 3) & 63;
    int f = idx >> 9;
    int ks = f % 6, wq = f / 6;
    int q = wq & 3, w = wq >> 2;
    int gate = 16 * (8 * q + w) + (l & 15);
    int k = 32 * ks + ((l >> 4) << 3) + j;
    float v = (k < 64) ? Wih0[gate * 64 + k] : Whh0[gate * 128 + (k - 64)];
    PA[idx] = (_Float16)v;
  } else if (idx < 98304 + 131072) {
    int i = idx - 98304;
    int j = i & 7, l = (i >> 3) & 63;
    int f = i >> 9;
    int ks = f & 7, wq = f >> 3;
    int q = wq & 3, w = wq >> 2;
    int gate = 16 * (8 * q + w) + (l & 15);
    int k = 32 * ks + ((l >> 4) << 3) + j;
    float v = (k < 128) ? Wih1[gate * 128 + k] : Whh1[gate * 128 + (k - 128)];
    PB[i] = (_Float16)v;
  }
}

// 64 blocks x 1024 threads (16 waves, 4/SIMD via waves_per_eu(4,4) -> 128
// regs/wave, the R8-spill fix). LAYER-SPLIT: waves 0-7 = layer0, 8-15 =
// layer1; each SIMD hosts 2 L0 + 2 L1 waves -> trans/MFMA/LDS/L2 overlap
// across roles (R13 post-mortem: trans quarter-rate is the fixed cost;
// per-wave cell work halves here). Fused: iter j = L0 step j || L1 step j-1,
// ONE barrier/iter (R8-verified schedule). Wave w of its group owns units
// [16w,16w+16) x 4 gates. Weights: Whh1 LDS-resident (128 KB, R13 layout);
// W0 / Wih1 compiler-rematerialized from L2 (~160 KB/step, R13-measured OK;
// NO anchors -- at 128 regs they would spill). c fp32 in regs; lane-local.
__global__ __attribute__((amdgpu_waves_per_eu(4, 4))) __launch_bounds__(1024)
void lstm_block(
    const float* __restrict__ x,
    const _Float16* __restrict__ PA, const _Float16* __restrict__ PB,
    const float* __restrict__ b0, const float* __restrict__ b1,
    const float* __restrict__ Wout, const float* __restrict__ bout,
    float* __restrict__ out) {
  extern __shared__ char smem[];
  h8v* whh = (h8v*)smem;  // Whh1 B-frags: [32 wq][4 ks4][64 l] = 128 KB
  _Float16(*h0t)[4][64][8] = (_Float16(*)[4][64][8])(smem + 131072);          // [2][4][64][8] 8 KB
  _Float16(*h1t)[4][64][8] = (_Float16(*)[4][64][8])(smem + 131072 + 8192);   // 8 KB
  _Float16(*xt)[2][64][8]  = (_Float16(*)[2][64][8])(smem + 131072 + 16384);  // [2][2][64][8] 4 KB

  const int tid = threadIdx.x;
  const int g = blockIdx.x;
  const int wv = tid >> 6, l = tid & 63;
  const int lo = l & 15, hi = l >> 4;
  const bool isL0 = (wv < 8);
  const int w = isL0 ? wv : (wv - 8);
  const int unit = 16 * w + lo;
  const int kb_w = w >> 1;
  const int sub_w = (2 * w + (lo >> 3)) & 3;
  const int lanep = sub_w * 16 + hi * 4;  // + r
  const int jw = lo & 7;

  const h8v* PAv = (const h8v*)PA;
  const h8v* PBv = (const h8v*)PB;

  float br[4];
#pragma unroll
  for (int q = 0; q < 4; ++q)
    br[q] = isL0 ? b0[unit + 128 * q] : b1[unit + 128 * q];
  float cs[4] = {0.f, 0.f, 0.f, 0.f};

  // ---- stage Whh1 fragments into LDS ----
  for (int i = tid; i < 8192; i += 1024) {
    int l2 = i & 63, f = i >> 6;
    int ks4 = f & 3, wq = f >> 2;
    whh[i] = PBv[(wq * 8 + 4 + ks4) * 64 + l2];
  }
  // ---- zero h0t/h1t, stage x(0) ----
  {
    unsigned int* z0 = (unsigned int*)h0t;
    unsigned int* z1 = (unsigned int*)h1t;
    for (int i = tid; i < 2048; i += 1024) { z0[i] = 0u; z1[i] = 0u; }
    if (tid < 512) {
      int row = tid >> 5, kk = (tid & 31) << 1;
      const float* xp = x + (((long)(g * 16 + row)) * T_STEPS + 0) * 64 + kk;
      float2 v = *(const float2*)xp;
      h2v pxv; pxv.x = (_Float16)v.x; pxv.y = (_Float16)v.y;
      *(h2v*)&xt[0][kk >> 5][(((kk >> 3) & 3) * 16) + row][kk & 7] = pxv;
    }
  }
  __syncthreads();

  // Fused: iter j = L0 step j (waves 0-7) || L1 step j-1 (waves 8-15).
  for (int j = 0; j <= T_STEPS; ++j) {
    const int p = j & 1;

    if (isL0) {
      if (j < T_STEPS) {
        // ---- layer 0, step j: reads h0t[p], xt[p]; writes h0t[p^1] ----
        h8v h00 = *(const h8v*)&h0t[p][0][l][0];
        h8v h01 = *(const h8v*)&h0t[p][1][l][0];
        h8v h02 = *(const h8v*)&h0t[p][2][l][0];
        h8v h03 = *(const h8v*)&h0t[p][3][l][0];
        h8v ax0 = *(const h8v*)&xt[p][0][l][0];
        h8v ax1 = *(const h8v*)&xt[p][1][l][0];
        f4v acc[4];
#pragma unroll
        for (int q = 0; q < 4; ++q) {
          const h8v* wp = PAv + (long)((w * 4 + q) * 6) * 64 + l;
          h8v w0 = wp[0], w1 = wp[64], w2 = wp[128];
          h8v w3 = wp[192], w4 = wp[256], w5 = wp[320];
          f4v z = {br[q], br[q], br[q], br[q]};
          z = __builtin_amdgcn_mfma_f32_16x16x32_f16(ax0, w0, z, 0, 0, 0);
          z = __builtin_amdgcn_mfma_f32_16x16x32_f16(ax1, w1, z, 0, 0, 0);
          z = __builtin_amdgcn_mfma_f32_16x16x32_f16(h00, w2, z, 0, 0, 0);
          z = __builtin_amdgcn_mfma_f32_16x16x32_f16(h01, w3, z, 0, 0, 0);
          z = __builtin_amdgcn_mfma_f32_16x16x32_f16(h02, w4, z, 0, 0, 0);
          z = __builtin_amdgcn_mfma_f32_16x16x32_f16(h03, w5, z, 0, 0, 0);
          acc[q] = z;
        }
#pragma unroll
        for (int r = 0; r < 4; ++r) {
          float cn = sigf(acc[1][r]) * cs[r] + sigf(acc[0][r]) * tanh_(acc[2][r]);
          cs[r] = cn;
          float hv = sigf(acc[3][r]) * tanh_(cn);
          h0t[p ^ 1][kb_w][lanep + r][jw] = (_Float16)hv;
        }
        if (j + 1 < T_STEPS) {  // stage x(j+1) -> xt[p^1] (all 512 L0 threads)
          int row = tid >> 5, kk = (tid & 31) << 1;
          const float* xp = x + (((long)(g * 16 + row)) * T_STEPS + (j + 1)) * 64 + kk;
          float2 v = *(const float2*)xp;
          h2v pxv; pxv.x = (_Float16)v.x; pxv.y = (_Float16)v.y;
          *(h2v*)&xt[p ^ 1][kk >> 5][(((kk >> 3) & 3) * 16) + row][kk & 7] = pxv;
        }
      }
    } else {
      if (j >= 1) {
        // ---- layer 1, step j-1: reads h0t[p] (=h0(j-1)), h1t[p]; writes h1t[p^1] ----
        h8v h00 = *(const h8v*)&h0t[p][0][l][0];
        h8v h01 = *(const h8v*)&h0t[p][1][l][0];
        h8v h02 = *(const h8v*)&h0t[p][2][l][0];
        h8v h03 = *(const h8v*)&h0t[p][3][l][0];
        h8v f10 = *(const h8v*)&h1t[p][0][l][0];
        h8v f11 = *(const h8v*)&h1t[p][1][l][0];
        h8v f12 = *(const h8v*)&h1t[p][2][l][0];
        h8v f13 = *(const h8v*)&h1t[p][3][l][0];
        f4v acc[4];
#pragma unroll
        for (int q = 0; q < 4; ++q) {
          const h8v* wip = PBv + (long)((w * 4 + q) * 8) * 64 + l;
          h8v wi0 = wip[0], wi1 = wip[64], wi2 = wip[128], wi3 = wip[192];
          const h8v* wb = &whh[((w * 4 + q) * 4) * 64 + l];
          h8v wh0 = wb[0];
          h8v wh1 = wb[64];
          h8v wh2 = wb[128];
          h8v wh3 = wb[192];
          f4v z = {br[q], br[q], br[q], br[q]};
          z = __builtin_amdgcn_mfma_f32_16x16x32_f16(h00, wi0, z, 0, 0, 0);
          z = __builtin_amdgcn_mfma_f32_16x16x32_f16(h01, wi1, z, 0, 0, 0);
          z = __builtin_amdgcn_mfma_f32_16x16x32_f16(h02, wi2, z, 0, 0, 0);
          z = __builtin_amdgcn_mfma_f32_16x16x32_f16(h03, wi3, z, 0, 0, 0);
          z = __builtin_amdgcn_mfma_f32_16x16x32_f16(f10, wh0, z, 0, 0, 0);
          z = __builtin_amdgcn_mfma_f32_16x16x32_f16(f11, wh1, z, 0, 0, 0);
          z = __builtin_amdgcn_mfma_f32_16x16x32_f16(f12, wh2, z, 0, 0, 0);
          z = __builtin_amdgcn_mfma_f32_16x16x32_f16(f13, wh3, z, 0, 0, 0);
          acc[q] = z;
        }
#pragma unroll
        for (int r = 0; r < 4; ++r) {
          float cn = sigf(acc[1][r]) * cs[r] + sigf(acc[0][r]) * tanh_(acc[2][r]);
          cs[r] = cn;
          float hv = sigf(acc[3][r]) * tanh_(cn);
          h1t[p ^ 1][kb_w][lanep + r][jw] = (_Float16)hv;
        }
      }
    }
    __syncthreads();
  }

  // ---- output projection: y = h1(T-1) . Wout^T + bout ; h1(T-1) in h1t[1] ----
  if (tid < 16) {
    float acc = bout[0];
#pragma unroll 4
    for (int u = 0; u < 128; ++u) {
      float hval = (float)h1t[1][u >> 5][(((u >> 3) & 3) * 16) + tid][u & 7];
      acc = fmaf(hval, Wout[u], acc);
    }
    out[g * 16 + tid] = acc;
  }
}

}  // namespace

extern "C" void kernel_launch(void* const* d_in, const int* in_sizes, int n_in,
                              void* d_out, int out_size, void* d_ws, size_t ws_size,
                              hipStream_t stream) {
  const float* x    = (const float*)d_in[0];
  const float* Wih0 = (const float*)d_in[1];
  const float* Whh0 = (const float*)d_in[2];
  const float* b0   = (const float*)d_in[3];
  const float* Wih1 = (const float*)d_in[4];
  const float* Whh1 = (const float*)d_in[5];
  const float* b1   = (const float*)d_in[6];
  const float* Wout = (const float*)d_in[7];
  const float* bout = (const float*)d_in[8];
  float* out = (float*)d_out;

  char* ws = (char*)d_ws;
  _Float16* PA = (_Float16*)ws;             // 196608 B
  _Float16* PB = (_Float16*)(ws + 196608);  // 262144 B

  const int lds_bytes = 131072 + 8192 + 8192 + 4096;  // 151552
  hipFuncSetAttribute((const void*)lstm_block,
                      hipFuncAttributeMaxDynamicSharedMemorySize, lds_bytes);

  pack_w<<<dim3(896), dim3(256), 0, stream>>>(Wih0, Whh0, Wih1, Whh1, PA, PB);
  lstm_block<<<dim3(64), dim3(1024), lds_bytes, stream>>>(
      x, PA, PB, b0, b1, Wout, bout, out);
}